// Round 7
// baseline (378.648 us; speedup 1.0000x reference)
//
#include <hip/hip_runtime.h>

// Workspace layout (float offsets)
#define WS_M2 0          // 16384 floats  (512 x 32)
#define WS_N2 16384      // 2048  floats  (64 x 32)
#define WS_WT 18432      // 131072 floats (32 x 4096), W transposed: Wt[r*4096+o]
#define WS_Z  149504     // 32768 floats  (1024 x 32)
#define WS_P  182272     // 2048 blocks x 2048 floats = 4 Mi floats (T3 partials)

// ---------------------------------------------------------------------------
// Kernel A: collapse TT factor chains into small dense matrices.
// ---------------------------------------------------------------------------
__global__ __launch_bounds__(256) void precompute_kernel(
    const float* __restrict__ f0, const float* __restrict__ f1,
    const float* __restrict__ f2, const float* __restrict__ f3,
    const float* __restrict__ f4, const float* __restrict__ g0,
    const float* __restrict__ g1, const float* __restrict__ g2,
    float* __restrict__ ws)
{
    __shared__ float sA[8192];
    const int t = threadIdx.x;
    const int blk = blockIdx.x;
    if (blk < 8) {
        for (int i = t; i < 2048; i += 256) {
            int a01 = i >> 5, r2 = i & 31;
            int a0 = a01 >> 3, a1 = a01 & 7;
            float s = 0.f;
            #pragma unroll
            for (int r1 = 0; r1 < 32; ++r1)
                s += f0[a0*32 + r1] * f1[r1*256 + a1*32 + r2];
            sA[i] = s;
        }
        __syncthreads();
        for (int i = t; i < 2048; i += 256) {
            int a012 = blk*64 + (i >> 5), r3 = i & 31;
            int a01 = a012 >> 3, a2 = a012 & 7;
            float s = 0.f;
            #pragma unroll
            for (int r2 = 0; r2 < 32; ++r2)
                s += sA[a01*32 + r2] * f2[r2*256 + a2*32 + r3];
            ws[WS_M2 + a012*32 + r3] = s;
        }
    } else if (blk == 8) {
        for (int i = t; i < 2048; i += 256) {
            int a34 = i >> 5, s2 = i & 31;
            int a3 = a34 >> 3, a4 = a34 & 7;
            float s = 0.f;
            #pragma unroll
            for (int s1 = 0; s1 < 32; ++s1)
                s += f3[a3*32 + s1] * f4[s1*256 + a4*32 + s2];
            ws[WS_N2 + i] = s;
        }
    } else {
        const int j = blk - 9;   // 0..31, o-slice
        for (int i = t; i < 8192; i += 256) {
            int o01 = i >> 5, q = i & 31;
            int o0 = o01 >> 4, o1 = o01 & 15;
            float s = 0.f;
            #pragma unroll
            for (int p = 0; p < 32; ++p)
                s += g0[o0*32 + p] * g1[p*512 + o1*32 + q];
            sA[i] = s;
        }
        __syncthreads();
        for (int i = t; i < 4096; i += 256) {
            int o = j*128 + (i >> 5);
            int r = i & 31;
            int o01 = o >> 4, o2 = o & 15;
            float s = 0.f;
            #pragma unroll
            for (int q = 0; q < 32; ++q)
                s += sA[o01*32 + q] * g2[q*512 + o2*32 + r];
            ws[WS_WT + r*4096 + o] = s;
        }
    }
}

// ---------------------------------------------------------------------------
// Kernel P1: phase 1 only, barrier-free k-loop, maximal memory concurrency.
//   Grid 2048: block = (b = blk>>1, k-half h = blk&1), 256 threads, LDS 8KB.
//   Thread (m4 = t&15, rs = t>>4): acc[m 4][r 2]; per k ONE float4 x load +
//   ONE float2 M2 load (lane-group broadcast), 8-deep unroll -> ~16 loads in
//   flight per thread, ~28 waves/CU resident, no __syncthreads in the loop,
//   no scalar-load data dependence, nothing to sink.
//   Epilogue: LDS bounce -> coalesced partial write (8KB) to ws.
// ---------------------------------------------------------------------------
__global__ __launch_bounds__(256, 6) void phase1_kernel(
    const float* __restrict__ x, const float* __restrict__ ws_in,
    float* __restrict__ ws_out)
{
    __shared__ float sm[2048];
    const int t  = threadIdx.x;
    const int b  = blockIdx.x >> 1;
    const int h  = blockIdx.x & 1;
    const int m4 = t & 15;
    const int rs = t >> 4;         // r-pair index 0..15

    const float4* __restrict__ x4 = (const float4*)(x + (size_t)b * 32768) + h*4096;
    const float2* __restrict__ m2 = (const float2*)(ws_in + WS_M2) + h*4096;

    float a00=0.f,a01=0.f,a10=0.f,a11=0.f,a20=0.f,a21=0.f,a30=0.f,a31=0.f;

    for (int kk = 0; kk < 256; kk += 8) {
        float4 xv[8]; float2 wv[8];
        #pragma unroll
        for (int i = 0; i < 8; ++i) xv[i] = x4[(kk + i)*16 + m4];
        #pragma unroll
        for (int i = 0; i < 8; ++i) wv[i] = m2[(kk + i)*16 + rs];
        #pragma unroll
        for (int i = 0; i < 8; ++i) {
            a00 += xv[i].x * wv[i].x; a01 += xv[i].x * wv[i].y;
            a10 += xv[i].y * wv[i].x; a11 += xv[i].y * wv[i].y;
            a20 += xv[i].z * wv[i].x; a21 += xv[i].z * wv[i].y;
            a30 += xv[i].w * wv[i].x; a31 += xv[i].w * wv[i].y;
        }
    }

    // bounce through LDS for a coalesced 8KB partial write
    sm[(m4*4 + 0)*32 + rs*2 + 0] = a00; sm[(m4*4 + 0)*32 + rs*2 + 1] = a01;
    sm[(m4*4 + 1)*32 + rs*2 + 0] = a10; sm[(m4*4 + 1)*32 + rs*2 + 1] = a11;
    sm[(m4*4 + 2)*32 + rs*2 + 0] = a20; sm[(m4*4 + 2)*32 + rs*2 + 1] = a21;
    sm[(m4*4 + 3)*32 + rs*2 + 0] = a30; sm[(m4*4 + 3)*32 + rs*2 + 1] = a31;
    __syncthreads();
    float4* p4 = (float4*)(ws_out + WS_P + (size_t)blockIdx.x * 2048);
    const float4* s4 = (const float4*)sm;
    p4[t] = s4[t];
    p4[256 + t] = s4[256 + t];
}

// ---------------------------------------------------------------------------
// Kernel B2: per b — reduce the 2 k-half partials, then phases 3 & 4.
//   T3[m,r] = P0+P1; T5[r3,s2] = sum_m T3[m,r3]*N2[m,s2];
//   z[ro] = sum_k T5[k]*core[k,ro].
// ---------------------------------------------------------------------------
__global__ __launch_bounds__(256) void phase34_kernel(
    const float* __restrict__ core, const float* __restrict__ ws,
    float* __restrict__ zout)
{
    __shared__ float buf[5632];  // T3[0..2048) N2[2048..4096) T5[4096..5120)
                                 // spart[5120..5632)
    const int t = threadIdx.x;
    const int b = blockIdx.x;

    {
        const float4* p0 = (const float4*)(ws + WS_P + (size_t)(b*2    ) * 2048);
        const float4* p1 = (const float4*)(ws + WS_P + (size_t)(b*2 + 1) * 2048);
        const float4* n24 = (const float4*)(ws + WS_N2);
        float4* d = (float4*)buf;
        #pragma unroll
        for (int i = 0; i < 2; ++i) {
            float4 u = p0[i*256 + t], v = p1[i*256 + t];
            u.x+=v.x; u.y+=v.y; u.z+=v.z; u.w+=v.w;
            d[i*256 + t] = u;
            d[512 + i*256 + t] = n24[i*256 + t];
        }
    }
    __syncthreads();

    // phase 3: T5[r3,s2] -> buf[4096..5120)
    {
        const int r3  = t >> 3;
        const int s2b = (t & 7) * 4;
        float a0=0.f, a1=0.f, a2=0.f, a3=0.f;
        #pragma unroll 8
        for (int m = 0; m < 64; ++m) {
            float av = buf[m*32 + r3];
            const float* n = &buf[2048 + m*32 + s2b];
            a0 += av*n[0]; a1 += av*n[1]; a2 += av*n[2]; a3 += av*n[3];
        }
        float* d = &buf[4096 + r3*32 + s2b];
        d[0]=a0; d[1]=a1; d[2]=a2; d[3]=a3;
    }
    __syncthreads();

    // phase 4: z[ro] = sum_k T5[k] * core[k,ro]
    {
        const int ro2 = t & 15;
        const int kc  = t >> 4;
        const float2* core2 = (const float2*)core;
        float s0 = 0.f, s1 = 0.f;
        const int k0 = kc * 64;
        for (int k = k0; k < k0 + 64; ++k) {
            float tv = buf[4096 + k];
            float2 cv = core2[k*16 + ro2];
            s0 += tv*cv.x; s1 += tv*cv.y;
        }
        buf[5120 + kc*32 + ro2*2 + 0] = s0;
        buf[5120 + kc*32 + ro2*2 + 1] = s1;
    }
    __syncthreads();
    if (t < 32) {
        float s = 0.f;
        #pragma unroll
        for (int kc = 0; kc < 16; ++kc) s += buf[5120 + kc*32 + t];
        zout[b*32 + t] = s;
    }
}

// ---------------------------------------------------------------------------
// Kernel C: out[b,o] = sum_r z[b,r]*Wt[r,o] + bias[o]
// ---------------------------------------------------------------------------
__global__ __launch_bounds__(256) void out_kernel(
    const float* __restrict__ ws, const float* __restrict__ bias,
    float* __restrict__ out)
{
    __shared__ float sW[8192];   // Wt tile [32][256]
    __shared__ float sZt[2176];  // z tile transposed [32 ro][68]
    __shared__ float sB[256];
    const int t  = threadIdx.x;
    const int bt = blockIdx.x;
    const int ot = blockIdx.y;

    {
        const float4* wt4 = (const float4*)(ws + WS_WT);
        float4* d = (float4*)sW;
        #pragma unroll
        for (int i = 0; i < 8; ++i) {
            int idx = i*256 + t;
            int ro = idx >> 6, oc = idx & 63;
            d[idx] = wt4[ro*1024 + ot*64 + oc];
        }
    }
    {
        const float4* z4 = (const float4*)(ws + WS_Z) + bt*512;
        #pragma unroll
        for (int i = 0; i < 2; ++i) {
            int idx = i*256 + t;
            int bl = idx >> 3, r4 = idx & 7;
            float4 v = z4[idx];
            sZt[(r4*4 + 0)*68 + bl] = v.x;
            sZt[(r4*4 + 1)*68 + bl] = v.y;
            sZt[(r4*4 + 2)*68 + bl] = v.z;
            sZt[(r4*4 + 3)*68 + bl] = v.w;
        }
    }
    if (t < 64) {
        const float4* b4 = (const float4*)bias + ot*64;
        ((float4*)sB)[t] = b4[t];
    }
    __syncthreads();

    const int oc = t & 63;
    const int bg = t >> 6;
    const float4* sW4 = (const float4*)sW;
    const float4 bv = ((const float4*)sB)[oc];
    float4* out4 = (float4*)out;

    for (int bi = 0; bi < 16; bi += 4) {
        const int bl = bg*16 + bi;
        float4 a0 = bv, a1 = bv, a2 = bv, a3 = bv;
        #pragma unroll
        for (int ro = 0; ro < 32; ++ro) {
            float4 w = sW4[ro*64 + oc];
            float4 z = *(const float4*)&sZt[ro*68 + bl];
            a0.x += z.x*w.x; a0.y += z.x*w.y; a0.z += z.x*w.z; a0.w += z.x*w.w;
            a1.x += z.y*w.x; a1.y += z.y*w.y; a1.z += z.y*w.z; a1.w += z.y*w.w;
            a2.x += z.z*w.x; a2.y += z.z*w.y; a2.z += z.z*w.z; a2.w += z.z*w.w;
            a3.x += z.w*w.x; a3.y += z.w*w.y; a3.z += z.w*w.z; a3.w += z.w*w.w;
        }
        const size_t obase = (size_t)(bt*64 + bl) * 1024 + ot*64 + oc;
        out4[obase + 0*1024] = a0;
        out4[obase + 1*1024] = a1;
        out4[obase + 2*1024] = a2;
        out4[obase + 3*1024] = a3;
    }
}

extern "C" void kernel_launch(void* const* d_in, const int* in_sizes, int n_in,
                              void* d_out, int out_size, void* d_ws, size_t ws_size,
                              hipStream_t stream)
{
    const float* x    = (const float*)d_in[0];
    const float* f0   = (const float*)d_in[1];
    const float* f1   = (const float*)d_in[2];
    const float* f2   = (const float*)d_in[3];
    const float* f3   = (const float*)d_in[4];
    const float* f4   = (const float*)d_in[5];
    const float* core = (const float*)d_in[6];
    const float* g0   = (const float*)d_in[7];
    const float* g1   = (const float*)d_in[8];
    const float* g2   = (const float*)d_in[9];
    const float* bias = (const float*)d_in[10];
    float* ws  = (float*)d_ws;
    float* out = (float*)d_out;

    precompute_kernel<<<41, 256, 0, stream>>>(f0, f1, f2, f3, f4, g0, g1, g2, ws);
    phase1_kernel<<<2048, 256, 0, stream>>>(x, ws, ws);
    phase34_kernel<<<1024, 256, 0, stream>>>(core, ws, ws + WS_Z);
    out_kernel<<<dim3(16, 16), 256, 0, stream>>>(ws, bias, out);
}